// Round 7
// baseline (663.023 us; speedup 1.0000x reference)
//
#include <hip/hip_runtime.h>
#include <math.h>

// ---------------- problem constants ----------------
// b=1, t=16, ch_in=10, h=w=24, t_de=16, ch_de=12, K=5, N=25
// hw=576, M = 14400; out: 27648 + loss = 27649 floats

typedef __attribute__((ext_vector_type(8))) short sh8;
typedef __attribute__((ext_vector_type(4))) float f32x4;

// ---------------- workspace layout (byte offsets) ----------------
#define OFF_PART 0UL              // 37,748,736 (max: conv2/3 16 splits x 1024x576x4)
#define OFF_X2T  37748736UL       // 26,542,080 (288 chunks x 92160)
#define OFF_WTT  37748736UL       // overlaps X2T (X2T dead when WTT written)
#define OFF_ACT  64290816UL       // 2,359,296
#define OFF_DN   66650112UL       // 11,059,200
#define OFF_OB   77709312UL       // 2,764,800
#define OFF_MN   80474112UL       // 16,128
#define OFF_MX   80490240UL       // 16,128
#define OFF_LP   80506368UL       // 2,304
// total ~80.5 MB (within known-safe 102 MB)

// X2T chunk layout: [kc][hi: 576x80B][lo: 576x80B]  (92160 B per chunk)

// ---------------- helpers ----------------
__device__ inline void glds16(const void* gsrc, void* ldst) {
    __builtin_amdgcn_global_load_lds((const __attribute__((address_space(1))) void*)gsrc,
                                     (__attribute__((address_space(3))) void*)ldst, 16, 0, 0);
}

// ---------------- min/max per pixel for the 7 normalization groups ----------------
__global__ __launch_bounds__(64) void minmax_kernel(const float* __restrict__ design,
                                                    float* __restrict__ mn_o,
                                                    float* __restrict__ mx_o) {
    int p = blockIdx.x;
    int py = p / 24, px = p % 24;
    int lane = threadIdx.x;
    float mn[7], mx[7];
#pragma unroll
    for (int g = 0; g < 7; g++) { mn[g] = 1e30f; mx[g] = -1e30f; }
    for (int e = lane; e < 400; e += 64) {
        int n = e / 16, td = e % 16;
        int yy = py + n / 5 - 2, xx = px + n % 5 - 2;
        bool ok = (yy >= 0 && yy < 24 && xx >= 0 && xx < 24);
#pragma unroll
        for (int cd = 1; cd < 12; cd++) {
            float v = ok ? design[(td * 12 + cd) * 576 + yy * 24 + xx] : 0.0f;
            int g = (cd <= 3) ? 0 : (cd == 4) ? 1 : (cd <= 7) ? 2 : 3 + (cd - 8);
            mn[g] = fminf(mn[g], v);
            mx[g] = fmaxf(mx[g], v);
        }
    }
#pragma unroll
    for (int s = 32; s >= 1; s >>= 1) {
#pragma unroll
        for (int g = 0; g < 7; g++) {
            mn[g] = fminf(mn[g], __shfl_xor(mn[g], s));
            mx[g] = fmaxf(mx[g], __shfl_xor(mx[g], s));
        }
    }
    if (lane == 0) {
#pragma unroll
        for (int g = 0; g < 7; g++) {
            mn_o[p * 7 + g] = mn[g];
            mx_o[p * 7 + g] = mx[g];
        }
    }
}

// ---------------- normalized d: dn[p][n][td][cd] ----------------
__global__ void dnorm_kernel(const float* __restrict__ design,
                             const float* __restrict__ mn,
                             const float* __restrict__ mx,
                             float* __restrict__ dn) {
    int idx = blockIdx.x * 256 + threadIdx.x;
    if (idx >= 14400 * 192) return;
    int cd = idx % 12;
    int td = (idx / 12) % 16;
    int n  = (idx / 192) % 25;
    int p  = idx / 4800;
    int py = p / 24, px = p % 24;
    int yy = py + n / 5 - 2, xx = px + n % 5 - 2;
    float v = (yy >= 0 && yy < 24 && xx >= 0 && xx < 24)
                  ? design[(td * 12 + cd) * 576 + yy * 24 + xx] : 0.0f;
    if (cd >= 1) {
        int g = (cd <= 3) ? 0 : (cd == 4) ? 1 : (cd <= 7) ? 2 : 3 + (cd - 8);
        float a = mn[p * 7 + g], b = mx[p * 7 + g];
        v = (v - a) / (b - a + 0.001f);
    }
    dn[idx] = v;
}

// ---------------- im2col: act fp32 [C][24][24] -> X2T bf16 hi/lo chunk-major ----------------
__global__ __launch_bounds__(256) void im2col_kernel(const float* __restrict__ act,
                                                     char* __restrict__ x2t, int nrows) {
    int row = blockIdx.x * 256 + threadIdx.x;
    if (row >= nrows) return;
    int kc = row / 576, px = row % 576;
    int y = px / 24, x = px % 24;
    int k0 = kc * 32;
    int ic = k0 / 9;
    int tap = k0 - ic * 9;
    sh8 hv[4], lv[4];
#pragma unroll
    for (int e = 0; e < 32; ++e) {
        int dy = tap / 3, dx = tap - dy * 3;
        int yy = y + dy - 1, xx = x + dx - 1;
        float v = (yy >= 0 && yy < 24 && xx >= 0 && xx < 24)
                      ? act[ic * 576 + yy * 24 + xx] : 0.0f;
        unsigned u = __builtin_bit_cast(unsigned, v);
        hv[e / 8][e % 8] = (short)(u >> 16);
        float fh = __builtin_bit_cast(float, u & 0xFFFF0000u);
        lv[e / 8][e % 8] = (short)(__builtin_bit_cast(unsigned, v - fh) >> 16);
        if (++tap == 9) { tap = 0; ++ic; }
    }
    char* dst = x2t + (long)kc * 92160 + (long)px * 80;
#pragma unroll
    for (int s4 = 0; s4 < 4; ++s4) {
        *(sh8*)(dst + s4 * 16) = hv[s4];
        *(sh8*)(dst + 46080 + s4 * 16) = lv[s4];
    }
}

// ---------------- sum K-splits + bias + leaky -> act fp32 ----------------
__global__ void finalize_kernel(const float* __restrict__ part,
                                const float* __restrict__ bias,
                                float* __restrict__ act, int total, int nsplit) {
    int idx = blockIdx.x * 256 + threadIdx.x;
    if (idx >= total) return;
    float s = 0.0f;
    for (int k = 0; k < nsplit; k++) s += part[(long)k * total + idx];
    s += bias[idx / 576];
    act[idx] = s >= 0.0f ? s : 0.01f * s;
}

// ---------------- MFMA GEMM conv (v6): 8-wave, A+B double-buffered, issue-early pipeline ----
// Block: 512 thr, 128 oc x 288 px; 8 waves = 4 wo x 2 wp; wave = 32 oc x 144 px = 2ot x 9j.
// Per chunk t: issue glds B[t+1]->buf^1 + A[t+1] reg loads FIRST; then ds_read frags of t
// + 54 MFMAs/wave; then vmcnt(0) (loads landed under compute), convert A, ds_write buf^1,
// ONE barrier. The wait sits AFTER compute -> staging latency fully hidden.
__global__ __launch_bounds__(512, 1)
void conv_mfma6_kernel(const char* __restrict__ x2t,
                       const float* __restrict__ wgt,   // [cout][K] fp32, K = cin*9
                       float* __restrict__ part,        // [ksplit][cout][576]
                       int K, int cps, int cout) {
    __shared__ __align__(1024) char sB[2][46080];   // per buf: hi @0 (23040), lo @23040
    __shared__ __align__(1024) char sA[2][16384];   // per buf: hi[128][64B] @0, lo @8192

    const int tid = threadIdx.x;
    const int lane = tid & 63;
    const int w = tid >> 6;           // 0..7
    const int wo = w >> 1, wp = w & 1;
    const int q = lane >> 4, ln15 = lane & 15;
    const int ocb = blockIdx.x, pxh = blockIdx.y, s = blockIdx.z;
    const int c0 = s * cps;

    // A staging map: thread -> (oc row 0..127, k-granule 0..3 of 8 floats)
    const int st_oc = tid >> 2;
    const int kq = tid & 3;
    const float* wrow = wgt + (long)(ocb * 128 + st_oc) * K + kq * 8;
    const int wslot = (((kq) + (st_oc >> 1)) & 3) << 4;
    char* const awr_hi0 = sA[0] + st_oc * 64 + wslot;

    // A fragment read offsets (slot-swizzled, ~2-way banks)
    int aoff[2];
#pragma unroll
    for (int ot = 0; ot < 2; ++ot) {
        int oc = wo * 32 + ot * 16 + ln15;
        aoff[ot] = oc * 64 + (((q + (oc >> 1)) & 3) << 4);
    }
    const int bbase = (wp * 144 + ln15) * 80 + q * 16;

    f32x4 acc[2][9];
#pragma unroll
    for (int a = 0; a < 2; ++a)
#pragma unroll
        for (int j = 0; j < 9; ++j) acc[a][j] = f32x4{0.f, 0.f, 0.f, 0.f};

    // ---- prologue: stage chunk c0 into buf 0 ----
    {
        const char* bsrc = x2t + (long)c0 * 92160 + pxh * 23040;
        for (int it = w; it < 45; it += 8) {
            int boff = it * 1024 + lane * 16;
            const char* src = (boff < 23040) ? bsrc + boff
                                             : bsrc + 46080 + (boff - 23040);
            glds16(src, sB[0] + it * 1024);
        }
        const float* p = wrow + (long)c0 * 32;
        float4 a0 = *(const float4*)(p);
        float4 a1 = *(const float4*)(p + 4);
        float av[8] = {a0.x, a0.y, a0.z, a0.w, a1.x, a1.y, a1.z, a1.w};
        sh8 h8, l8;
#pragma unroll
        for (int e = 0; e < 8; ++e) {
            unsigned u = __builtin_bit_cast(unsigned, av[e]);
            h8[e] = (short)(u >> 16);
            float fh = __builtin_bit_cast(float, u & 0xFFFF0000u);
            l8[e] = (short)(__builtin_bit_cast(unsigned, av[e] - fh) >> 16);
        }
        *(sh8*)(awr_hi0) = h8;
        *(sh8*)(awr_hi0 + 8192) = l8;
    }
    asm volatile("s_waitcnt vmcnt(0)" ::: "memory");
    __syncthreads();

#pragma unroll 1
    for (int t = 0; t < cps; ++t) {
        const int cur = t & 1;
        const bool pf = (t + 1 < cps);
        float4 a0, a1;
        // ---- issue next-chunk loads FIRST (complete under this chunk's compute) ----
        if (pf) {
            const long cc1 = (long)(c0 + t + 1);
            const char* bsrc = x2t + cc1 * 92160 + pxh * 23040;
            char* bdst = sB[cur ^ 1];
            for (int it = w; it < 45; it += 8) {
                int boff = it * 1024 + lane * 16;
                const char* src = (boff < 23040) ? bsrc + boff
                                                 : bsrc + 46080 + (boff - 23040);
                glds16(src, bdst + it * 1024);
            }
            const float* p = wrow + cc1 * 32;
            a0 = *(const float4*)(p);
            a1 = *(const float4*)(p + 4);
        }
        // ---- compute chunk t from buf[cur] ----
        const char* sAc = sA[cur];
        const char* sBc = sB[cur];
        sh8 ah[2], al[2];
#pragma unroll
        for (int ot = 0; ot < 2; ++ot) {
            ah[ot] = *(const sh8*)(sAc + aoff[ot]);
            al[ot] = *(const sh8*)(sAc + 8192 + aoff[ot]);
        }
#pragma unroll
        for (int j = 0; j < 9; ++j) {
            int ba = bbase + j * 1280;
            sh8 bh = *(const sh8*)(sBc + ba);
            sh8 bl = *(const sh8*)(sBc + 23040 + ba);
#pragma unroll
            for (int ot = 0; ot < 2; ++ot) {
                acc[ot][j] = __builtin_amdgcn_mfma_f32_16x16x32_bf16(ah[ot], bh, acc[ot][j], 0, 0, 0);
                acc[ot][j] = __builtin_amdgcn_mfma_f32_16x16x32_bf16(al[ot], bh, acc[ot][j], 0, 0, 0);
                acc[ot][j] = __builtin_amdgcn_mfma_f32_16x16x32_bf16(ah[ot], bl, acc[ot][j], 0, 0, 0);
            }
        }
        // ---- drain (cheap now), stage A[t+1] into buf^1, one barrier ----
        if (pf) {
            asm volatile("s_waitcnt vmcnt(0)" ::: "memory");
            float av[8] = {a0.x, a0.y, a0.z, a0.w, a1.x, a1.y, a1.z, a1.w};
            sh8 h8, l8;
#pragma unroll
            for (int e = 0; e < 8; ++e) {
                unsigned u = __builtin_bit_cast(unsigned, av[e]);
                h8[e] = (short)(u >> 16);
                float fh = __builtin_bit_cast(float, u & 0xFFFF0000u);
                l8[e] = (short)(__builtin_bit_cast(unsigned, av[e] - fh) >> 16);
            }
            char* hb = sA[cur ^ 1] + st_oc * 64 + wslot;
            *(sh8*)(hb) = h8;
            *(sh8*)(hb + 8192) = l8;
            __syncthreads();
        }
    }
    // epilogue: C row=oc (q*4+vr), col=px (ln15)
#pragma unroll
    for (int ot = 0; ot < 2; ++ot) {
        int oc0 = ocb * 128 + wo * 32 + ot * 16 + q * 4;
#pragma unroll
        for (int j = 0; j < 9; ++j) {
            int px = pxh * 288 + wp * 144 + j * 16 + ln15;
#pragma unroll
            for (int vr = 0; vr < 4; ++vr)
                part[((long)s * cout + oc0 + vr) * 576 + px] = acc[ot][j][vr];
        }
    }
}

// ---------------- tanh + sum splits + transpose: part -> wtT[576][6400] ----------------
__global__ __launch_bounds__(256) void tanh_tr_kernel(const float* __restrict__ part,
                                                      const float* __restrict__ bias,
                                                      float* __restrict__ wtT, int nsplit) {
    __shared__ float tile[64][65];
    int oc0 = blockIdx.x * 64, p0 = blockIdx.y * 64;
    int tx = threadIdx.x, ty = threadIdx.y;
#pragma unroll
    for (int k = 0; k < 16; k++) {
        int row = ty + k * 4;
        float s = 0.f;
        for (int sp = 0; sp < nsplit; ++sp)
            s += part[((long)sp * 6400 + oc0 + row) * 576 + p0 + tx];
        tile[row][tx] = tanhf(s + bias[oc0 + row]);
    }
    __syncthreads();
#pragma unroll
    for (int k = 0; k < 16; k++) {
        int rr = ty + k * 4;
        wtT[(long)(p0 + rr) * 6400 + oc0 + tx] = tile[tx][rr];
    }
}

// ---------------- per-pixel stage: Wm, XTW, A, B, solve, o, loss partial ----------------
__global__ __launch_bounds__(256) void stagec_kernel(const float* __restrict__ dn,
                                                     const float* __restrict__ wtT,
                                                     const float* __restrict__ xin,
                                                     const float* __restrict__ gt,
                                                     float* __restrict__ ob,
                                                     float* __restrict__ lp) {
    int p = blockIdx.x;
    int py = p / 24, px = p % 24;
    int tid = threadIdx.x;
    __shared__ float sX[4800];
    __shared__ float sW[6400];
    __shared__ float sY[1200];
    __shared__ float sP[192];
    __shared__ float sXTW[192];
    __shared__ float sA[144];
    __shared__ float sB[36];
    __shared__ double dA[144];
    __shared__ double db[36];
    __shared__ float spara[36];
    __shared__ float sred[256];

    for (int e = tid; e < 4800; e += 256) sX[e] = dn[(long)p * 4800 + e];
    for (int e = tid; e < 6400; e += 256) sW[e] = wtT[(long)p * 6400 + e];
    for (int e = tid; e < 1200; e += 256) {
        int n = e / 48, t = (e % 48) / 3, ch = e % 3;
        int yy = py + n / 5 - 2, xx = px + n % 5 - 2;
        sY[e] = (yy >= 0 && yy < 24 && xx >= 0 && xx < 24)
                    ? xin[(t * 10 + ch) * 576 + yy * 24 + xx] : 0.0f;
    }
    if (tid < 144) sA[tid] = 0.0f;
    if (tid < 36) sB[tid] = 0.0f;
    __syncthreads();

    for (int n = 0; n < 25; n++) {
        const float* X = sX + n * 192;
        const float* W = sW + n * 256;
        if (tid < 192) {
            int c = tid >> 4, j = tid & 15;
            float s = 0.0f;
#pragma unroll
            for (int t = 0; t < 16; t++) s = fmaf(X[t * 12 + c], W[t * 16 + j], s);
            sP[tid] = s;
        }
        __syncthreads();
        if (tid < 192) {
            int c = tid >> 4, u = tid & 15;
            float s = X[u * 12 + c];
#pragma unroll
            for (int j = 0; j < 16; j++) s = fmaf(sP[c * 16 + j], W[u * 16 + j], s);
            sXTW[tid] = s;
        }
        __syncthreads();
        if (tid < 144) {
            int c = tid / 12, d2 = tid % 12;
            float s = 0.0f;
#pragma unroll
            for (int t = 0; t < 16; t++) s = fmaf(sXTW[c * 16 + t], X[t * 12 + d2], s);
            sA[tid] += s;
        } else if (tid < 180) {
            int e = tid - 144;
            int c = e / 3, ch = e % 3;
            float s = 0.0f;
#pragma unroll
            for (int t = 0; t < 16; t++) s = fmaf(sXTW[c * 16 + t], sY[n * 48 + t * 3 + ch], s);
            sB[e] += s;
        }
        __syncthreads();
    }

    if (tid < 144) dA[tid] = (double)sA[tid] + ((tid % 13 == 0) ? 0.01 : 0.0);
    if (tid < 36) db[tid] = (double)sB[tid];
    __syncthreads();

    if (tid == 0) {
        for (int kk = 0; kk < 12; kk++) {
            double d = dA[kk * 12 + kk];
            for (int q2 = 0; q2 < kk; q2++) d -= dA[kk * 12 + q2] * dA[kk * 12 + q2];
            d = sqrt(d);
            dA[kk * 12 + kk] = d;
            double inv = 1.0 / d;
            for (int i = kk + 1; i < 12; i++) {
                double s = dA[i * 12 + kk];
                for (int q2 = 0; q2 < kk; q2++) s -= dA[i * 12 + q2] * dA[kk * 12 + q2];
                dA[i * 12 + kk] = s * inv;
            }
        }
        for (int ch = 0; ch < 3; ch++) {
            double t2[12];
            for (int i = 0; i < 12; i++) {
                double s = db[i * 3 + ch];
                for (int q2 = 0; q2 < i; q2++) s -= dA[i * 12 + q2] * t2[q2];
                t2[i] = s / dA[i * 12 + i];
            }
            for (int i = 11; i >= 0; i--) {
                double s = t2[i];
                for (int q2 = i + 1; q2 < 12; q2++) s -= dA[q2 * 12 + i] * t2[q2];
                t2[i] = s / dA[i * 12 + i];
            }
            for (int i = 0; i < 12; i++) spara[i * 3 + ch] = (float)t2[i];
        }
    }
    __syncthreads();

    float lsum = 0.0f;
    for (int e = tid; e < 1200; e += 256) {
        int n = e / 48, td = (e % 48) / 3, ch = e % 3;
        float s = 0.0f;
#pragma unroll
        for (int c = 0; c < 12; c++) s = fmaf(sX[n * 192 + td * 12 + c], spara[c * 3 + ch], s);
        ob[((long)(p * 25 + n)) * 48 + td * 3 + ch] = s;
        int yy = py + n / 5 - 2, xx = px + n % 5 - 2;
        float rv = (yy >= 0 && yy < 24 && xx >= 0 && xx < 24)
                       ? gt[(td * 3 + ch) * 576 + yy * 24 + xx] : 0.0f;
        lsum += fabsf(s - rv);
    }
    sred[tid] = lsum;
    __syncthreads();
    for (int s = 128; s >= 1; s >>= 1) {
        if (tid < s) sred[tid] += sred[tid + s];
        __syncthreads();
    }
    if (tid == 0) lp[p] = sred[0];
}

// ---------------- fold (overlap-add) + normalize ----------------
__global__ void fold_kernel(const float* __restrict__ ob, float* __restrict__ out) {
    int idx = blockIdx.x * 256 + threadIdx.x;
    if (idx >= 27648) return;
    int td = idx / 1728;
    int rem = idx % 1728;
    int ch = rem / 576;
    int p = rem % 576;
    int y = p / 24, x = p % 24;
    float num = 0.0f;
    int den = 0;
    for (int i = 0; i < 5; i++) {
        int yy = y + 2 - i;
        if (yy < 0 || yy >= 24) continue;
        for (int j = 0; j < 5; j++) {
            int xx = x + 2 - j;
            if (xx < 0 || xx >= 24) continue;
            num += ob[((long)((yy * 24 + xx) * 25 + i * 5 + j)) * 48 + td * 3 + ch];
            den++;
        }
    }
    out[idx] = num / (float)den;
}

// ---------------- final loss reduce ----------------
__global__ __launch_bounds__(64) void loss_kernel(const float* __restrict__ lp,
                                                  float* __restrict__ out) {
    int t = threadIdx.x;
    float s = 0.0f;
    for (int e = t; e < 576; e += 64) s += lp[e];
#pragma unroll
    for (int d = 32; d >= 1; d >>= 1) s += __shfl_xor(s, d);
    if (t == 0) out[27648] = s / 691200.0f;
}

// ---------------- launch ----------------
extern "C" void kernel_launch(void* const* d_in, const int* in_sizes, int n_in,
                              void* d_out, int out_size, void* d_ws, size_t ws_size,
                              hipStream_t stream) {
    const float* x      = (const float*)d_in[0];
    const float* design = (const float*)d_in[1];
    const float* gt     = (const float*)d_in[2];
    const float* w1     = (const float*)d_in[3];
    const float* b1     = (const float*)d_in[4];
    const float* w2     = (const float*)d_in[5];
    const float* b2     = (const float*)d_in[6];
    const float* w3     = (const float*)d_in[7];
    const float* b3     = (const float*)d_in[8];
    const float* wf     = (const float*)d_in[9];
    const float* bf     = (const float*)d_in[10];
    float* out = (float*)d_out;
    char* wsb  = (char*)d_ws;

    float* part = (float*)(wsb + OFF_PART);
    char*  x2t  = wsb + OFF_X2T;
    float* wtT  = (float*)(wsb + OFF_WTT);   // overlaps X2T (dead by then)
    float* act  = (float*)(wsb + OFF_ACT);
    float* dn   = (float*)(wsb + OFF_DN);
    float* ob   = (float*)(wsb + OFF_OB);
    float* mn   = (float*)(wsb + OFF_MN);
    float* mx   = (float*)(wsb + OFF_MX);
    float* lp   = (float*)(wsb + OFF_LP);

    minmax_kernel<<<576, 64, 0, stream>>>(design, mn, mx);
    dnorm_kernel<<<10800, 256, 0, stream>>>(design, mn, mx, dn);

    // conv1: K=1440 (45 chunks), ksplit=15 x cps=3 -> 240 blocks
    im2col_kernel<<<102, 256, 0, stream>>>(x, x2t, 45 * 576);
    conv_mfma6_kernel<<<dim3(8, 2, 15), 512, 0, stream>>>(x2t, w1, part, 1440, 3, 1024);
    finalize_kernel<<<2304, 256, 0, stream>>>(part, b1, act, 589824, 15);
    // conv2: K=9216 (288 chunks), ksplit=16 x cps=18 -> 256 blocks (1/CU, single round)
    im2col_kernel<<<648, 256, 0, stream>>>(act, x2t, 288 * 576);
    conv_mfma6_kernel<<<dim3(8, 2, 16), 512, 0, stream>>>(x2t, w2, part, 9216, 18, 1024);
    finalize_kernel<<<2304, 256, 0, stream>>>(part, b2, act, 589824, 16);
    // conv3
    im2col_kernel<<<648, 256, 0, stream>>>(act, x2t, 288 * 576);
    conv_mfma6_kernel<<<dim3(8, 2, 16), 512, 0, stream>>>(x2t, w3, part, 9216, 18, 1024);
    finalize_kernel<<<2304, 256, 0, stream>>>(part, b3, act, 589824, 16);
    // convf: cout=6400, ksplit=2 x cps=144 -> 200 blocks (single round)
    im2col_kernel<<<648, 256, 0, stream>>>(act, x2t, 288 * 576);
    conv_mfma6_kernel<<<dim3(50, 2, 2), 512, 0, stream>>>(x2t, wf, part, 9216, 144, 6400);
    tanh_tr_kernel<<<dim3(100, 9), dim3(64, 4), 0, stream>>>(part, bf, wtT, 2);

    stagec_kernel<<<576, 256, 0, stream>>>(dn, wtT, x, gt, ob, lp);
    fold_kernel<<<108, 256, 0, stream>>>(ob, out);
    loss_kernel<<<1, 64, 0, stream>>>(lp, out);
}

// Round 8
// 593.702 us; speedup vs baseline: 1.1168x; 1.1168x over previous
//
#include <hip/hip_runtime.h>
#include <math.h>

// ---------------- problem constants ----------------
// b=1, t=16, ch_in=10, h=w=24, t_de=16, ch_de=12, K=5, N=25
// hw=576, M = 14400; out: 27648 + loss = 27649 floats

typedef __attribute__((ext_vector_type(8))) short sh8;
typedef __attribute__((ext_vector_type(4))) float f32x4;

// ---------------- workspace layout (byte offsets) ----------------
#define OFF_PART 0UL              // 58,982,400 (convf: 4 splits x 6400x576x4)
#define OFF_X2T  58982400UL       // 21,233,664 (288 chunks x 73728)
#define OFF_WTT  58982400UL       // overlaps X2T (X2T dead when WTT written)
#define OFF_ACT  80216064UL       // 2,359,296
#define OFF_DN   82575360UL       // 11,059,200
#define OFF_OB   93634560UL       // 2,764,800
#define OFF_MN   96399360UL       // 16,128
#define OFF_MX   96415488UL       // 16,128
#define OFF_LP   96431616UL       // 2,304
// total ~96.4 MB (within known-safe 102 MB)

// X2T layout: [kc][pg(36)][plane(2: hi,lo)][q(4)][px16(16)][16B]
//   chunk stride 36*2048 = 73728 B; pg block 2048 B; plane 1024 B.
//   A wave's B fragment (16 px, one plane) = ONE contiguous 1024-B load (lane*16).

// ---------------- min/max per pixel for the 7 normalization groups ----------------
__global__ __launch_bounds__(64) void minmax_kernel(const float* __restrict__ design,
                                                    float* __restrict__ mn_o,
                                                    float* __restrict__ mx_o) {
    int p = blockIdx.x;
    int py = p / 24, px = p % 24;
    int lane = threadIdx.x;
    float mn[7], mx[7];
#pragma unroll
    for (int g = 0; g < 7; g++) { mn[g] = 1e30f; mx[g] = -1e30f; }
    for (int e = lane; e < 400; e += 64) {
        int n = e / 16, td = e % 16;
        int yy = py + n / 5 - 2, xx = px + n % 5 - 2;
        bool ok = (yy >= 0 && yy < 24 && xx >= 0 && xx < 24);
#pragma unroll
        for (int cd = 1; cd < 12; cd++) {
            float v = ok ? design[(td * 12 + cd) * 576 + yy * 24 + xx] : 0.0f;
            int g = (cd <= 3) ? 0 : (cd == 4) ? 1 : (cd <= 7) ? 2 : 3 + (cd - 8);
            mn[g] = fminf(mn[g], v);
            mx[g] = fmaxf(mx[g], v);
        }
    }
#pragma unroll
    for (int s = 32; s >= 1; s >>= 1) {
#pragma unroll
        for (int g = 0; g < 7; g++) {
            mn[g] = fminf(mn[g], __shfl_xor(mn[g], s));
            mx[g] = fmaxf(mx[g], __shfl_xor(mx[g], s));
        }
    }
    if (lane == 0) {
#pragma unroll
        for (int g = 0; g < 7; g++) {
            mn_o[p * 7 + g] = mn[g];
            mx_o[p * 7 + g] = mx[g];
        }
    }
}

// ---------------- normalized d: dn[p][n][td][cd] ----------------
__global__ void dnorm_kernel(const float* __restrict__ design,
                             const float* __restrict__ mn,
                             const float* __restrict__ mx,
                             float* __restrict__ dn) {
    int idx = blockIdx.x * 256 + threadIdx.x;
    if (idx >= 14400 * 192) return;
    int cd = idx % 12;
    int td = (idx / 12) % 16;
    int n  = (idx / 192) % 25;
    int p  = idx / 4800;
    int py = p / 24, px = p % 24;
    int yy = py + n / 5 - 2, xx = px + n % 5 - 2;
    float v = (yy >= 0 && yy < 24 && xx >= 0 && xx < 24)
                  ? design[(td * 12 + cd) * 576 + yy * 24 + xx] : 0.0f;
    if (cd >= 1) {
        int g = (cd <= 3) ? 0 : (cd == 4) ? 1 : (cd <= 7) ? 2 : 3 + (cd - 8);
        float a = mn[p * 7 + g], b = mx[p * 7 + g];
        v = (v - a) / (b - a + 0.001f);
    }
    dn[idx] = v;
}

// ---------------- im2col: act fp32 [C][24][24] -> X2T (frag-coalesced layout) ----------------
__global__ __launch_bounds__(256) void im2col_kernel(const float* __restrict__ act,
                                                     char* __restrict__ x2t, int nrows) {
    int row = blockIdx.x * 256 + threadIdx.x;
    if (row >= nrows) return;
    int kc = row / 576, px = row % 576;
    int y = px / 24, x = px % 24;
    int k0 = kc * 32;
    int ic = k0 / 9;
    int tap = k0 - ic * 9;
    sh8 hv[4], lv[4];
#pragma unroll
    for (int e = 0; e < 32; ++e) {
        int dy = tap / 3, dx = tap - dy * 3;
        int yy = y + dy - 1, xx = x + dx - 1;
        float v = (yy >= 0 && yy < 24 && xx >= 0 && xx < 24)
                      ? act[ic * 576 + yy * 24 + xx] : 0.0f;
        unsigned u = __builtin_bit_cast(unsigned, v);
        hv[e / 8][e % 8] = (short)(u >> 16);
        float fh = __builtin_bit_cast(float, u & 0xFFFF0000u);
        lv[e / 8][e % 8] = (short)(__builtin_bit_cast(unsigned, v - fh) >> 16);
        if (++tap == 9) { tap = 0; ++ic; }
    }
    int pg = px >> 4, l15 = px & 15;
    char* dst = x2t + (long)kc * 73728 + pg * 2048 + l15 * 16;
#pragma unroll
    for (int q = 0; q < 4; ++q) {
        *(sh8*)(dst + q * 256) = hv[q];
        *(sh8*)(dst + 1024 + q * 256) = lv[q];
    }
}

// ---------------- sum K-splits + bias + leaky -> act fp32 ----------------
__global__ void finalize_kernel(const float* __restrict__ part,
                                const float* __restrict__ bias,
                                float* __restrict__ act, int total, int nsplit) {
    int idx = blockIdx.x * 256 + threadIdx.x;
    if (idx >= total) return;
    float s = 0.0f;
    for (int k = 0; k < nsplit; k++) s += part[(long)k * total + idx];
    s += bias[idx / 576];
    act[idx] = s >= 0.0f ? s : 0.01f * s;
}

// ---------------- MFMA GEMM conv (v7): B in registers, A-only LDS ----------------
// Block: 256 thr = 4 waves (wo x wp); wave: 64 oc (4 ot) x 144 px (9 j) of 16x16 tiles.
// B (acts): NEVER in LDS. bh[9] persistent regs, reloaded for chunk t+1 right after
//   last use (9-step lookahead); bl[3] rotating (depth 3; 9%3==0 -> exact rotation),
//   reloaded for j+3. Each load = one coalesced 1024-B global_load_dwordx4.
// A (weights): reg-stage 64B/thread fp32 -> cvt bf16 hi/lo -> ds_write, double-buffered
//   (2x16 KB), ONE barrier per chunk. Compiler-managed waitcnts throughout.
template<int SWZ>
__global__ __launch_bounds__(256, 2)
void conv_mfma7_kernel(const char* __restrict__ x2t,
                       const float* __restrict__ wgt,   // [cout][K] fp32, K = cin*9
                       float* __restrict__ part,        // [ksplit][cout][576]
                       int K, int cps, int cout) {
    __shared__ __align__(1024) char sA[2][16384];   // per buf: hi[128][64B] @0, lo @8192

    const int tid = threadIdx.x;
    const int lane = tid & 63;
    const int w = tid >> 6;
    const int wo = w >> 1, wp = w & 1;
    const int q = lane >> 4, ln15 = lane & 15;
    const int lane16 = lane * 16;

    int ocb, pxh, s;
    if (SWZ) {
        int g = blockIdx.x;               // 400 blocks: 50 ocb x 2 pxh x 4 s
        int xcd = g & 7, slot = g >> 3;   // pxh-pairs land on one XCD
        int p = xcd + 8 * (slot >> 1);    // 0..199
        ocb = p % 50; s = p / 50; pxh = slot & 1;
    } else {
        ocb = blockIdx.x; pxh = blockIdx.y; s = blockIdx.z;
    }
    const int c0 = s * cps;
    const int cend = c0 + cps - 1;

    // A staging map: thread -> (oc row 0..127, 16-float half)
    const int st_oc = tid >> 1, st_h = tid & 1;
    const float* wrow = wgt + (long)(ocb * 128 + st_oc) * K + st_h * 16;
    const int wslot0 = (((st_h * 2 + 0) + (st_oc >> 1)) & 3) << 4;
    const int wslot1 = (((st_h * 2 + 1) + (st_oc >> 1)) & 3) << 4;

    // A fragment read offsets (slot-swizzled)
    int aoff[4];
#pragma unroll
    for (int ot = 0; ot < 4; ++ot) {
        int oc = wo * 64 + ot * 16 + ln15;
        aoff[ot] = oc * 64 + (((q + (oc >> 1)) & 3) << 4);
    }

    // B base for this wave's 9 pixel-groups
    const char* bbase = x2t + (long)(pxh * 18 + wp * 9) * 2048;

    f32x4 acc[4][9];
#pragma unroll
    for (int a = 0; a < 4; ++a)
#pragma unroll
        for (int j = 0; j < 9; ++j) acc[a][j] = f32x4{0.f, 0.f, 0.f, 0.f};

    // ---- prologue: B regs for chunk c0; stage A[c0] into buf 0 ----
    sh8 bh[9], bl[3];
    {
        const char* bc = bbase + (long)c0 * 73728;
#pragma unroll
        for (int j = 0; j < 9; ++j) bh[j] = *(const sh8*)(bc + j * 2048 + lane16);
#pragma unroll
        for (int j = 0; j < 3; ++j) bl[j] = *(const sh8*)(bc + j * 2048 + 1024 + lane16);
    }
    {
        const float* p = wrow + (long)c0 * 32;
        float4 a0 = *(const float4*)(p);
        float4 a1 = *(const float4*)(p + 4);
        float4 a2 = *(const float4*)(p + 8);
        float4 a3 = *(const float4*)(p + 12);
        float av[16] = {a0.x, a0.y, a0.z, a0.w, a1.x, a1.y, a1.z, a1.w,
                        a2.x, a2.y, a2.z, a2.w, a3.x, a3.y, a3.z, a3.w};
        sh8 h8[2], l8[2];
#pragma unroll
        for (int e = 0; e < 16; ++e) {
            unsigned u = __builtin_bit_cast(unsigned, av[e]);
            h8[e / 8][e % 8] = (short)(u >> 16);
            float fh = __builtin_bit_cast(float, u & 0xFFFF0000u);
            l8[e / 8][e % 8] = (short)(__builtin_bit_cast(unsigned, av[e] - fh) >> 16);
        }
        char* hb = sA[0] + st_oc * 64;
        *(sh8*)(hb + wslot0) = h8[0];
        *(sh8*)(hb + wslot1) = h8[1];
        *(sh8*)(hb + 8192 + wslot0) = l8[0];
        *(sh8*)(hb + 8192 + wslot1) = l8[1];
    }
    __syncthreads();

#pragma unroll 1
    for (int t = 0; t < cps; ++t) {
        const int cur = t & 1;
        const bool pf = (t + 1 < cps);
        const int cc1 = pf ? (c0 + t + 1) : cend;       // clamped next chunk
        const char* bcur  = bbase + (long)(c0 + t) * 73728;
        const char* bnext = bbase + (long)cc1 * 73728;

        // issue A[t+1] global loads early (hidden under j-loop)
        const float* ap = wrow + (long)cc1 * 32;
        float4 a0 = *(const float4*)(ap);
        float4 a1 = *(const float4*)(ap + 4);
        float4 a2 = *(const float4*)(ap + 8);
        float4 a3 = *(const float4*)(ap + 12);

        // A fragments from LDS buf[cur]
        const char* sAc = sA[cur];
        sh8 ah[4], al[4];
#pragma unroll
        for (int ot = 0; ot < 4; ++ot) {
            ah[ot] = *(const sh8*)(sAc + aoff[ot]);
            al[ot] = *(const sh8*)(sAc + 8192 + aoff[ot]);
        }

        // j-loop: 27 MFMA triples + in-flight B reloads
#pragma unroll
        for (int j = 0; j < 9; ++j) {
            const int sl = j % 3;
            sh8 bhj = bh[j];
            sh8 blj = bl[sl];
#pragma unroll
            for (int ot = 0; ot < 4; ++ot)
                acc[ot][j] = __builtin_amdgcn_mfma_f32_16x16x32_bf16(ah[ot], bhj, acc[ot][j], 0, 0, 0);
#pragma unroll
            for (int ot = 0; ot < 4; ++ot)
                acc[ot][j] = __builtin_amdgcn_mfma_f32_16x16x32_bf16(al[ot], bhj, acc[ot][j], 0, 0, 0);
#pragma unroll
            for (int ot = 0; ot < 4; ++ot)
                acc[ot][j] = __builtin_amdgcn_mfma_f32_16x16x32_bf16(ah[ot], blj, acc[ot][j], 0, 0, 0);
            // reload bh[j] for next chunk (9-step lookahead)
            bh[j] = *(const sh8*)(bnext + j * 2048 + lane16);
            // reload bl slot for position j+3 (3-step lookahead)
            const int jn = j + 3;
            const char* bs = (jn < 9) ? bcur : bnext;
            const int jj = (jn < 9) ? jn : jn - 9;
            bl[sl] = *(const sh8*)(bs + jj * 2048 + 1024 + lane16);
        }

        // stage A[t+1] into buf^1, one barrier
        if (pf) {
            float av[16] = {a0.x, a0.y, a0.z, a0.w, a1.x, a1.y, a1.z, a1.w,
                            a2.x, a2.y, a2.z, a2.w, a3.x, a3.y, a3.z, a3.w};
            sh8 h8[2], l8[2];
#pragma unroll
            for (int e = 0; e < 16; ++e) {
                unsigned u = __builtin_bit_cast(unsigned, av[e]);
                h8[e / 8][e % 8] = (short)(u >> 16);
                float fh = __builtin_bit_cast(float, u & 0xFFFF0000u);
                l8[e / 8][e % 8] = (short)(__builtin_bit_cast(unsigned, av[e] - fh) >> 16);
            }
            char* hb = sA[cur ^ 1] + st_oc * 64;
            *(sh8*)(hb + wslot0) = h8[0];
            *(sh8*)(hb + wslot1) = h8[1];
            *(sh8*)(hb + 8192 + wslot0) = l8[0];
            *(sh8*)(hb + 8192 + wslot1) = l8[1];
            __syncthreads();
        }
    }
    // epilogue: C row=oc (q*4+vr), col=px (ln15)
#pragma unroll
    for (int ot = 0; ot < 4; ++ot) {
        int oc0 = ocb * 128 + wo * 64 + ot * 16 + q * 4;
#pragma unroll
        for (int j = 0; j < 9; ++j) {
            int px = pxh * 288 + wp * 144 + j * 16 + ln15;
#pragma unroll
            for (int vr = 0; vr < 4; ++vr)
                part[((long)s * cout + oc0 + vr) * 576 + px] = acc[ot][j][vr];
        }
    }
}

// ---------------- tanh + sum splits + transpose: part -> wtT[576][6400] ----------------
__global__ __launch_bounds__(256) void tanh_tr_kernel(const float* __restrict__ part,
                                                      const float* __restrict__ bias,
                                                      float* __restrict__ wtT, int nsplit) {
    __shared__ float tile[64][65];
    int oc0 = blockIdx.x * 64, p0 = blockIdx.y * 64;
    int tx = threadIdx.x, ty = threadIdx.y;
#pragma unroll
    for (int k = 0; k < 16; k++) {
        int row = ty + k * 4;
        float s = 0.f;
        for (int sp = 0; sp < nsplit; ++sp)
            s += part[((long)sp * 6400 + oc0 + row) * 576 + p0 + tx];
        tile[row][tx] = tanhf(s + bias[oc0 + row]);
    }
    __syncthreads();
#pragma unroll
    for (int k = 0; k < 16; k++) {
        int rr = ty + k * 4;
        wtT[(long)(p0 + rr) * 6400 + oc0 + tx] = tile[tx][rr];
    }
}

// ---------------- per-pixel stage: Wm, XTW, A, B, solve, o, loss partial ----------------
__global__ __launch_bounds__(256) void stagec_kernel(const float* __restrict__ dn,
                                                     const float* __restrict__ wtT,
                                                     const float* __restrict__ xin,
                                                     const float* __restrict__ gt,
                                                     float* __restrict__ ob,
                                                     float* __restrict__ lp) {
    int p = blockIdx.x;
    int py = p / 24, px = p % 24;
    int tid = threadIdx.x;
    __shared__ float sX[4800];
    __shared__ float sW[6400];
    __shared__ float sY[1200];
    __shared__ float sP[192];
    __shared__ float sXTW[192];
    __shared__ float sA[144];
    __shared__ float sB[36];
    __shared__ double dA[144];
    __shared__ double db[36];
    __shared__ float spara[36];
    __shared__ float sred[256];

    for (int e = tid; e < 4800; e += 256) sX[e] = dn[(long)p * 4800 + e];
    for (int e = tid; e < 6400; e += 256) sW[e] = wtT[(long)p * 6400 + e];
    for (int e = tid; e < 1200; e += 256) {
        int n = e / 48, t = (e % 48) / 3, ch = e % 3;
        int yy = py + n / 5 - 2, xx = px + n % 5 - 2;
        sY[e] = (yy >= 0 && yy < 24 && xx >= 0 && xx < 24)
                    ? xin[(t * 10 + ch) * 576 + yy * 24 + xx] : 0.0f;
    }
    if (tid < 144) sA[tid] = 0.0f;
    if (tid < 36) sB[tid] = 0.0f;
    __syncthreads();

    for (int n = 0; n < 25; n++) {
        const float* X = sX + n * 192;
        const float* W = sW + n * 256;
        if (tid < 192) {
            int c = tid >> 4, j = tid & 15;
            float s = 0.0f;
#pragma unroll
            for (int t = 0; t < 16; t++) s = fmaf(X[t * 12 + c], W[t * 16 + j], s);
            sP[tid] = s;
        }
        __syncthreads();
        if (tid < 192) {
            int c = tid >> 4, u = tid & 15;
            float s = X[u * 12 + c];
#pragma unroll
            for (int j = 0; j < 16; j++) s = fmaf(sP[c * 16 + j], W[u * 16 + j], s);
            sXTW[tid] = s;
        }
        __syncthreads();
        if (tid < 144) {
            int c = tid / 12, d2 = tid % 12;
            float s = 0.0f;
#pragma unroll
            for (int t = 0; t < 16; t++) s = fmaf(sXTW[c * 16 + t], X[t * 12 + d2], s);
            sA[tid] += s;
        } else if (tid < 180) {
            int e = tid - 144;
            int c = e / 3, ch = e % 3;
            float s = 0.0f;
#pragma unroll
            for (int t = 0; t < 16; t++) s = fmaf(sXTW[c * 16 + t], sY[n * 48 + t * 3 + ch], s);
            sB[e] += s;
        }
        __syncthreads();
    }

    if (tid < 144) dA[tid] = (double)sA[tid] + ((tid % 13 == 0) ? 0.01 : 0.0);
    if (tid < 36) db[tid] = (double)sB[tid];
    __syncthreads();

    if (tid == 0) {
        for (int kk = 0; kk < 12; kk++) {
            double d = dA[kk * 12 + kk];
            for (int q2 = 0; q2 < kk; q2++) d -= dA[kk * 12 + q2] * dA[kk * 12 + q2];
            d = sqrt(d);
            dA[kk * 12 + kk] = d;
            double inv = 1.0 / d;
            for (int i = kk + 1; i < 12; i++) {
                double s = dA[i * 12 + kk];
                for (int q2 = 0; q2 < kk; q2++) s -= dA[i * 12 + q2] * dA[kk * 12 + q2];
                dA[i * 12 + kk] = s * inv;
            }
        }
        for (int ch = 0; ch < 3; ch++) {
            double t2[12];
            for (int i = 0; i < 12; i++) {
                double s = db[i * 3 + ch];
                for (int q2 = 0; q2 < i; q2++) s -= dA[i * 12 + q2] * t2[q2];
                t2[i] = s / dA[i * 12 + i];
            }
            for (int i = 11; i >= 0; i--) {
                double s = t2[i];
                for (int q2 = i + 1; q2 < 12; q2++) s -= dA[q2 * 12 + i] * t2[q2];
                t2[i] = s / dA[i * 12 + i];
            }
            for (int i = 0; i < 12; i++) spara[i * 3 + ch] = (float)t2[i];
        }
    }
    __syncthreads();

    float lsum = 0.0f;
    for (int e = tid; e < 1200; e += 256) {
        int n = e / 48, td = (e % 48) / 3, ch = e % 3;
        float s = 0.0f;
#pragma unroll
        for (int c = 0; c < 12; c++) s = fmaf(sX[n * 192 + td * 12 + c], spara[c * 3 + ch], s);
        ob[((long)(p * 25 + n)) * 48 + td * 3 + ch] = s;
        int yy = py + n / 5 - 2, xx = px + n % 5 - 2;
        float rv = (yy >= 0 && yy < 24 && xx >= 0 && xx < 24)
                       ? gt[(td * 3 + ch) * 576 + yy * 24 + xx] : 0.0f;
        lsum += fabsf(s - rv);
    }
    sred[tid] = lsum;
    __syncthreads();
    for (int s = 128; s >= 1; s >>= 1) {
        if (tid < s) sred[tid] += sred[tid + s];
        __syncthreads();
    }
    if (tid == 0) lp[p] = sred[0];
}

// ---------------- fold (overlap-add) + normalize ----------------
__global__ void fold_kernel(const float* __restrict__ ob, float* __restrict__ out) {
    int idx = blockIdx.x * 256 + threadIdx.x;
    if (idx >= 27648) return;
    int td = idx / 1728;
    int rem = idx % 1728;
    int ch = rem / 576;
    int p = rem % 576;
    int y = p / 24, x = p % 24;
    float num = 0.0f;
    int den = 0;
    for (int i = 0; i < 5; i++) {
        int yy = y + 2 - i;
        if (yy < 0 || yy >= 24) continue;
        for (int j = 0; j < 5; j++) {
            int xx = x + 2 - j;
            if (xx < 0 || xx >= 24) continue;
            num += ob[((long)((yy * 24 + xx) * 25 + i * 5 + j)) * 48 + td * 3 + ch];
            den++;
        }
    }
    out[idx] = num / (float)den;
}

// ---------------- final loss reduce ----------------
__global__ __launch_bounds__(64) void loss_kernel(const float* __restrict__ lp,
                                                  float* __restrict__ out) {
    int t = threadIdx.x;
    float s = 0.0f;
    for (int e = t; e < 576; e += 64) s += lp[e];
#pragma unroll
    for (int d = 32; d >= 1; d >>= 1) s += __shfl_xor(s, d);
    if (t == 0) out[27648] = s / 691200.0f;
}

// ---------------- launch ----------------
extern "C" void kernel_launch(void* const* d_in, const int* in_sizes, int n_in,
                              void* d_out, int out_size, void* d_ws, size_t ws_size,
                              hipStream_t stream) {
    const float* x      = (const float*)d_in[0];
    const float* design = (const float*)d_in[1];
    const float* gt     = (const float*)d_in[2];
    const float* w1     = (const float*)d_in[3];
    const float* b1     = (const float*)d_in[4];
    const float* w2     = (const float*)d_in[5];
    const float* b2     = (const float*)d_in[6];
    const float* w3     = (const float*)d_in[7];
    const float* b3     = (const float*)d_in[8];
    const float* wf     = (const float*)d_in[9];
    const float* bf     = (const float*)d_in[10];
    float* out = (float*)d_out;
    char* wsb  = (char*)d_ws;

    float* part = (float*)(wsb + OFF_PART);
    char*  x2t  = wsb + OFF_X2T;
    float* wtT  = (float*)(wsb + OFF_WTT);   // overlaps X2T (dead by then)
    float* act  = (float*)(wsb + OFF_ACT);
    float* dn   = (float*)(wsb + OFF_DN);
    float* ob   = (float*)(wsb + OFF_OB);
    float* mn   = (float*)(wsb + OFF_MN);
    float* mx   = (float*)(wsb + OFF_MX);
    float* lp   = (float*)(wsb + OFF_LP);

    minmax_kernel<<<576, 64, 0, stream>>>(design, mn, mx);
    dnorm_kernel<<<10800, 256, 0, stream>>>(design, mn, mx, dn);

    // conv1: K=1440 (45 chunks), ksplit=15 x cps=3
    im2col_kernel<<<102, 256, 0, stream>>>(x, x2t, 45 * 576);
    conv_mfma7_kernel<0><<<dim3(8, 2, 15), 256, 0, stream>>>(x2t, w1, part, 1440, 3, 1024);
    finalize_kernel<<<2304, 256, 0, stream>>>(part, b1, act, 589824, 15);
    // conv2: K=9216 (288 chunks), ksplit=16 x cps=18 -> 256 blocks
    im2col_kernel<<<648, 256, 0, stream>>>(act, x2t, 288 * 576);
    conv_mfma7_kernel<0><<<dim3(8, 2, 16), 256, 0, stream>>>(x2t, w2, part, 9216, 18, 1024);
    finalize_kernel<<<2304, 256, 0, stream>>>(part, b2, act, 589824, 16);
    // conv3
    im2col_kernel<<<648, 256, 0, stream>>>(act, x2t, 288 * 576);
    conv_mfma7_kernel<0><<<dim3(8, 2, 16), 256, 0, stream>>>(x2t, w3, part, 9216, 18, 1024);
    finalize_kernel<<<2304, 256, 0, stream>>>(part, b3, act, 589824, 16);
    // convf: cout=6400, ksplit=4 x cps=72; 1D grid with XCD pair-swizzle
    im2col_kernel<<<648, 256, 0, stream>>>(act, x2t, 288 * 576);
    conv_mfma7_kernel<1><<<400, 256, 0, stream>>>(x2t, wf, part, 9216, 72, 6400);
    tanh_tr_kernel<<<dim3(100, 9), dim3(64, 4), 0, stream>>>(part, bf, wtT, 4);

    stagec_kernel<<<576, 256, 0, stream>>>(dn, wtT, x, gt, ob, lp);
    fold_kernel<<<108, 256, 0, stream>>>(ob, out);
    loss_kernel<<<1, 64, 0, stream>>>(lp, out);
}

// Round 9
// 506.586 us; speedup vs baseline: 1.3088x; 1.1720x over previous
//
#include <hip/hip_runtime.h>
#include <math.h>

// ---------------- problem constants ----------------
// b=1, t=16, ch_in=10, h=w=24, t_de=16, ch_de=12, K=5, N=25
// hw=576, M = 14400; out: 27648 + loss = 27649 floats

typedef __attribute__((ext_vector_type(8))) short sh8;
typedef __attribute__((ext_vector_type(4))) float f32x4;

// ---------------- workspace layout (byte offsets) ----------------
#define OFF_PART 0UL              // 58,982,400 (convf: 4 splits x 6400x576x4)
#define OFF_X2T  58982400UL       // 21,233,664 (288 chunks x 73728)
#define OFF_WTT  58982400UL       // overlaps X2T (X2T dead when WTT written)
#define OFF_ACT  80216064UL       // 2,359,296
#define OFF_OB   82575360UL       // 2,764,800
#define OFF_LP   85340160UL       // 2,304
// total ~85.3 MB (within known-safe 96 MB)

// X2T layout: [kc][pg(36)][plane(2: hi,lo)][q(4)][px16(16)][16B]
//   chunk stride 36*2048 = 73728 B; pg block 2048 B; plane 1024 B.

// ---------------- helpers ----------------
__device__ inline void glds16(const void* gsrc, void* ldst) {
    __builtin_amdgcn_global_load_lds((const __attribute__((address_space(1))) void*)gsrc,
                                     (__attribute__((address_space(3))) void*)ldst, 16, 0, 0);
}

// ---------------- im2col: act fp32 [C][24][24] -> X2T (frag-coalesced layout) ----------------
__global__ __launch_bounds__(256) void im2col_kernel(const float* __restrict__ act,
                                                     char* __restrict__ x2t, int nrows) {
    int row = blockIdx.x * 256 + threadIdx.x;
    if (row >= nrows) return;
    int kc = row / 576, px = row % 576;
    int y = px / 24, x = px % 24;
    int k0 = kc * 32;
    int ic = k0 / 9;
    int tap = k0 - ic * 9;
    sh8 hv[4], lv[4];
#pragma unroll
    for (int e = 0; e < 32; ++e) {
        int dy = tap / 3, dx = tap - dy * 3;
        int yy = y + dy - 1, xx = x + dx - 1;
        float v = (yy >= 0 && yy < 24 && xx >= 0 && xx < 24)
                      ? act[ic * 576 + yy * 24 + xx] : 0.0f;
        unsigned u = __builtin_bit_cast(unsigned, v);
        hv[e / 8][e % 8] = (short)(u >> 16);
        float fh = __builtin_bit_cast(float, u & 0xFFFF0000u);
        lv[e / 8][e % 8] = (short)(__builtin_bit_cast(unsigned, v - fh) >> 16);
        if (++tap == 9) { tap = 0; ++ic; }
    }
    int pg = px >> 4, l15 = px & 15;
    char* dst = x2t + (long)kc * 73728 + pg * 2048 + l15 * 16;
#pragma unroll
    for (int q = 0; q < 4; ++q) {
        *(sh8*)(dst + q * 256) = hv[q];
        *(sh8*)(dst + 1024 + q * 256) = lv[q];
    }
}

// ---------------- sum K-splits + bias + leaky -> act fp32 ----------------
__global__ void finalize_kernel(const float* __restrict__ part,
                                const float* __restrict__ bias,
                                float* __restrict__ act, int total, int nsplit) {
    int idx = blockIdx.x * 256 + threadIdx.x;
    if (idx >= total) return;
    float s = 0.0f;
    for (int k = 0; k < nsplit; k++) s += part[(long)k * total + idx];
    s += bias[idx / 576];
    act[idx] = s >= 0.0f ? s : 0.01f * s;
}

// ---------------- MFMA GEMM conv (v8): r4 2-barrier structure, 4 blocks/CU ----------------
// Block: 256 thr = 4 waves; 128 oc x 144 px. Wave wo (0..3): 32 oc (2 ot) x 144 px (9 j).
// Per chunk: [bar] glds B (18x1024B, frag-coalesced) + reg-load A fp32 -> cvt bf16 hi/lo
// -> ds_write (slot-swizzled) -> vmcnt(0) -> [bar] -> 54 MFMA triples/wave.
// Single-buffered (34 KB LDS -> 4 blocks/CU); cross-block overlap hides the stage stall.
template<int SWZ>
__global__ __launch_bounds__(256, 4)
void conv_mfma8_kernel(const char* __restrict__ x2t,
                       const float* __restrict__ wgt,   // [cout][K] fp32, K = cin*9
                       float* __restrict__ part,        // [ksplit][cout][576]
                       int K, int cps, int cout) {
    __shared__ __align__(1024) char sB[18432];   // [j(9)][plane(2)][1024B]
    __shared__ __align__(1024) char sA[16384];   // hi[128][64B] @0, lo @8192

    const int tid = threadIdx.x;
    const int lane = tid & 63;
    const int w = tid >> 6;
    const int q = lane >> 4, ln15 = lane & 15;
    const int lane16 = lane * 16;

    int ocb, pxq, s;
    if (SWZ) {
        int g = blockIdx.x;               // 800 = 50 ocb x 4 pxq x 4 s
        int p = (g & 7) * 100 + (g >> 3); // bijective XCD-chunk map (800 = 8*100)
        ocb = p / 16;
        int rem = p % 16;
        s = rem >> 2; pxq = rem & 3;
    } else {
        ocb = blockIdx.x; pxq = blockIdx.y; s = blockIdx.z;
    }
    const int c0 = s * cps;

    // A staging map: thread -> (oc row 0..127, 16-float half)
    const int st_oc = tid >> 1, st_h = tid & 1;
    const float* wrow = wgt + (long)(ocb * 128 + st_oc) * K + st_h * 16;
    const int wslot0 = (((st_h * 2 + 0) + (st_oc >> 1)) & 3) << 4;
    const int wslot1 = (((st_h * 2 + 1) + (st_oc >> 1)) & 3) << 4;

    // A fragment read offsets (slot-swizzled)
    int aoff[2];
#pragma unroll
    for (int ot = 0; ot < 2; ++ot) {
        int oc = w * 32 + ot * 16 + ln15;
        aoff[ot] = oc * 64 + (((q + (oc >> 1)) & 3) << 4);
    }

    f32x4 acc[2][9];
#pragma unroll
    for (int a = 0; a < 2; ++a)
#pragma unroll
        for (int j = 0; j < 9; ++j) acc[a][j] = f32x4{0.f, 0.f, 0.f, 0.f};

#pragma unroll 1
    for (int t = 0; t < cps; ++t) {
        const int cc = c0 + t;
        __syncthreads();   // previous chunk's compute done
        // B: 18 plane-units of 1024 B, frag-coalesced
        const char* bsrc = x2t + (long)cc * 73728 + pxq * 18432;
        for (int u = w; u < 18; u += 4)
            glds16(bsrc + u * 1024 + lane16, sB + u * 1024);
        // A: reg-load fp32, convert to bf16 hi/lo, ds_write
        {
            const float* p = wrow + (long)cc * 32;
            float4 a0 = *(const float4*)(p);
            float4 a1 = *(const float4*)(p + 4);
            float4 a2 = *(const float4*)(p + 8);
            float4 a3 = *(const float4*)(p + 12);
            float av[16] = {a0.x, a0.y, a0.z, a0.w, a1.x, a1.y, a1.z, a1.w,
                            a2.x, a2.y, a2.z, a2.w, a3.x, a3.y, a3.z, a3.w};
            sh8 h8[2], l8[2];
#pragma unroll
            for (int e = 0; e < 16; ++e) {
                unsigned u = __builtin_bit_cast(unsigned, av[e]);
                h8[e / 8][e % 8] = (short)(u >> 16);
                float fh = __builtin_bit_cast(float, u & 0xFFFF0000u);
                l8[e / 8][e % 8] = (short)(__builtin_bit_cast(unsigned, av[e] - fh) >> 16);
            }
            char* hb = sA + st_oc * 64;
            *(sh8*)(hb + wslot0) = h8[0];
            *(sh8*)(hb + wslot1) = h8[1];
            *(sh8*)(hb + 8192 + wslot0) = l8[0];
            *(sh8*)(hb + 8192 + wslot1) = l8[1];
        }
        asm volatile("s_waitcnt vmcnt(0)" ::: "memory");
        __syncthreads();

        // compute
        sh8 ah[2], al[2];
#pragma unroll
        for (int ot = 0; ot < 2; ++ot) {
            ah[ot] = *(const sh8*)(sA + aoff[ot]);
            al[ot] = *(const sh8*)(sA + 8192 + aoff[ot]);
        }
#pragma unroll
        for (int j = 0; j < 9; ++j) {
            sh8 bh = *(const sh8*)(sB + j * 2048 + lane16);
            sh8 bl = *(const sh8*)(sB + j * 2048 + 1024 + lane16);
#pragma unroll
            for (int ot = 0; ot < 2; ++ot) {
                acc[ot][j] = __builtin_amdgcn_mfma_f32_16x16x32_bf16(ah[ot], bh, acc[ot][j], 0, 0, 0);
                acc[ot][j] = __builtin_amdgcn_mfma_f32_16x16x32_bf16(al[ot], bh, acc[ot][j], 0, 0, 0);
                acc[ot][j] = __builtin_amdgcn_mfma_f32_16x16x32_bf16(ah[ot], bl, acc[ot][j], 0, 0, 0);
            }
        }
    }
    // epilogue: C row=oc (q*4+vr), col=px (ln15)
#pragma unroll
    for (int ot = 0; ot < 2; ++ot) {
        int oc0 = ocb * 128 + w * 32 + ot * 16 + q * 4;
#pragma unroll
        for (int j = 0; j < 9; ++j) {
            int px = pxq * 144 + j * 16 + ln15;
#pragma unroll
            for (int vr = 0; vr < 4; ++vr)
                part[((long)s * cout + oc0 + vr) * 576 + px] = acc[ot][j][vr];
        }
    }
}

// ---------------- tanh + sum splits + transpose: part -> wtT[576][6400] ----------------
__global__ __launch_bounds__(256) void tanh_tr_kernel(const float* __restrict__ part,
                                                      const float* __restrict__ bias,
                                                      float* __restrict__ wtT, int nsplit) {
    __shared__ float tile[64][65];
    int oc0 = blockIdx.x * 64, p0 = blockIdx.y * 64;
    int tx = threadIdx.x, ty = threadIdx.y;
#pragma unroll
    for (int k = 0; k < 16; k++) {
        int row = ty + k * 4;
        float s = 0.f;
        for (int sp = 0; sp < nsplit; ++sp)
            s += part[((long)sp * 6400 + oc0 + row) * 576 + p0 + tx];
        tile[row][tx] = tanhf(s + bias[oc0 + row]);
    }
    __syncthreads();
#pragma unroll
    for (int k = 0; k < 16; k++) {
        int rr = ty + k * 4;
        wtT[(long)(p0 + rr) * 6400 + oc0 + tx] = tile[tx][rr];
    }
}

// ---------------- per-pixel stage: fused norm, Wm/XTW/A/B, parallel GJ solve, o, loss ----
__global__ __launch_bounds__(256) void stagec_kernel(const float* __restrict__ design,
                                                     const float* __restrict__ wtT,
                                                     const float* __restrict__ xin,
                                                     const float* __restrict__ gt,
                                                     float* __restrict__ ob,
                                                     float* __restrict__ lp) {
    int p = blockIdx.x;
    int py = p / 24, px = p % 24;
    int tid = threadIdx.x;
    int lane = tid & 63, wv = tid >> 6;
    __shared__ float sX[4800];
    __shared__ float sW[6400];
    __shared__ float sY[1200];
    __shared__ float sP[192];
    __shared__ float sXTW[192];
    __shared__ float sA[144];
    __shared__ float sB[36];
    __shared__ double dM[180];      // augmented [A | B], 12 x 15
    __shared__ float spara[36];
    __shared__ float sred[256];
    __shared__ float sMnW[28], sMxW[28], sMn[7], sMx[7];

    // ---- stage raw design window (zeros outside), W, Y ----
    for (int e = tid; e < 4800; e += 256) {
        int n = e / 192, r = e % 192, td = r / 12, cd = r % 12;
        int yy = py + n / 5 - 2, xx = px + n % 5 - 2;
        sX[e] = (yy >= 0 && yy < 24 && xx >= 0 && xx < 24)
                    ? design[(td * 12 + cd) * 576 + yy * 24 + xx] : 0.0f;
    }
    for (int e = tid; e < 6400; e += 256) sW[e] = wtT[(long)p * 6400 + e];
    for (int e = tid; e < 1200; e += 256) {
        int n = e / 48, t = (e % 48) / 3, ch = e % 3;
        int yy = py + n / 5 - 2, xx = px + n % 5 - 2;
        sY[e] = (yy >= 0 && yy < 24 && xx >= 0 && xx < 24)
                    ? xin[(t * 10 + ch) * 576 + yy * 24 + xx] : 0.0f;
    }
    if (tid < 144) sA[tid] = 0.0f;
    if (tid < 36) sB[tid] = 0.0f;
    __syncthreads();

    // ---- in-block min/max over the 7 normalization groups (zeros included) ----
    {
        float mn[7], mx[7];
#pragma unroll
        for (int g = 0; g < 7; g++) { mn[g] = 1e30f; mx[g] = -1e30f; }
        for (int e = tid; e < 4800; e += 256) {
            int cd = e % 12;
            if (cd >= 1) {
                int g = (cd <= 3) ? 0 : (cd == 4) ? 1 : (cd <= 7) ? 2 : 3 + (cd - 8);
                float v = sX[e];
                mn[g] = fminf(mn[g], v);
                mx[g] = fmaxf(mx[g], v);
            }
        }
#pragma unroll
        for (int s2 = 32; s2 >= 1; s2 >>= 1)
#pragma unroll
            for (int g = 0; g < 7; g++) {
                mn[g] = fminf(mn[g], __shfl_xor(mn[g], s2));
                mx[g] = fmaxf(mx[g], __shfl_xor(mx[g], s2));
            }
        if (lane == 0)
#pragma unroll
            for (int g = 0; g < 7; g++) { sMnW[wv * 7 + g] = mn[g]; sMxW[wv * 7 + g] = mx[g]; }
    }
    __syncthreads();
    if (tid < 7) {
        float a = fminf(fminf(sMnW[tid], sMnW[7 + tid]), fminf(sMnW[14 + tid], sMnW[21 + tid]));
        float b = fmaxf(fmaxf(sMxW[tid], sMxW[7 + tid]), fmaxf(sMxW[14 + tid], sMxW[21 + tid]));
        sMn[tid] = a; sMx[tid] = b;
    }
    __syncthreads();
    for (int e = tid; e < 4800; e += 256) {
        int cd = e % 12;
        if (cd >= 1) {
            int g = (cd <= 3) ? 0 : (cd == 4) ? 1 : (cd <= 7) ? 2 : 3 + (cd - 8);
            sX[e] = (sX[e] - sMn[g]) / (sMx[g] - sMn[g] + 0.001f);
        }
    }
    __syncthreads();

    // ---- per-window accumulation of A, B (3 barriers per n) ----
    for (int n = 0; n < 25; n++) {
        const float* X = sX + n * 192;
        const float* W = sW + n * 256;
        if (tid < 192) {                 // P = X^T W
            int c = tid >> 4, j = tid & 15;
            float s = 0.0f;
#pragma unroll
            for (int t = 0; t < 16; t++) s = fmaf(X[t * 12 + c], W[t * 16 + j], s);
            sP[tid] = s;
        }
        __syncthreads();
        if (tid < 192) {                 // XTW = P W^T + X^T
            int c = tid >> 4, u = tid & 15;
            float s = X[u * 12 + c];
#pragma unroll
            for (int j = 0; j < 16; j++) s = fmaf(sP[c * 16 + j], W[u * 16 + j], s);
            sXTW[tid] = s;
        }
        __syncthreads();
        if (tid < 144) {                 // A += XTW X
            int c = tid / 12, d2 = tid % 12;
            float s = 0.0f;
#pragma unroll
            for (int t = 0; t < 16; t++) s = fmaf(sXTW[c * 16 + t], X[t * 12 + d2], s);
            sA[tid] += s;
        } else if (tid < 180) {          // B += XTW Y
            int e = tid - 144;
            int c = e / 3, ch = e % 3;
            float s = 0.0f;
#pragma unroll
            for (int t = 0; t < 16; t++) s = fmaf(sXTW[c * 16 + t], sY[n * 48 + t * 3 + ch], s);
            sB[e] += s;
        }
        __syncthreads();
        // (no loop-end barrier: next P writes sP, whose readers finished at the XTW barrier)
    }

    // ---- parallel Gauss-Jordan in double: [A + 0.01 I | B] ----
    if (tid < 144) dM[(tid / 12) * 15 + (tid % 12)] = (double)sA[tid] + ((tid % 13 == 0) ? 0.01 : 0.0);
    if (tid < 36) dM[(tid / 3) * 15 + 12 + (tid % 3)] = (double)sB[tid];
    __syncthreads();
    {
        int rr = (tid < 180) ? tid / 15 : 11;
        int c2 = (tid < 180) ? tid % 15 : 14;
#pragma unroll 1
        for (int k = 0; k < 12; ++k) {
            double pinv = 1.0 / dM[k * 15 + k];
            double fkc = dM[k * 15 + c2] * pinv;
            double frk = dM[rr * 15 + k];
            double cur = dM[rr * 15 + c2];
            __syncthreads();
            if (tid < 180) dM[rr * 15 + c2] = (rr == k) ? fkc : fma(-frk, fkc, cur);
            __syncthreads();
        }
    }
    if (tid < 36) spara[tid] = (float)dM[(tid / 3) * 15 + 12 + (tid % 3)];
    __syncthreads();

    // ---- o = domain @ para, loss partial ----
    float lsum = 0.0f;
    for (int e = tid; e < 1200; e += 256) {
        int n = e / 48, td = (e % 48) / 3, ch = e % 3;
        float s = 0.0f;
#pragma unroll
        for (int c = 0; c < 12; c++) s = fmaf(sX[n * 192 + td * 12 + c], spara[c * 3 + ch], s);
        ob[((long)(p * 25 + n)) * 48 + td * 3 + ch] = s;
        int yy = py + n / 5 - 2, xx = px + n % 5 - 2;
        float rv = (yy >= 0 && yy < 24 && xx >= 0 && xx < 24)
                       ? gt[(td * 3 + ch) * 576 + yy * 24 + xx] : 0.0f;
        lsum += fabsf(s - rv);
    }
    sred[tid] = lsum;
    __syncthreads();
    for (int s = 128; s >= 1; s >>= 1) {
        if (tid < s) sred[tid] += sred[tid + s];
        __syncthreads();
    }
    if (tid == 0) lp[p] = sred[0];
}

// ---------------- fold (overlap-add) + normalize ----------------
__global__ void fold_kernel(const float* __restrict__ ob, float* __restrict__ out) {
    int idx = blockIdx.x * 256 + threadIdx.x;
    if (idx >= 27648) return;
    int td = idx / 1728;
    int rem = idx % 1728;
    int ch = rem / 576;
    int p = rem % 576;
    int y = p / 24, x = p % 24;
    float num = 0.0f;
    int den = 0;
    for (int i = 0; i < 5; i++) {
        int yy = y + 2 - i;
        if (yy < 0 || yy >= 24) continue;
        for (int j = 0; j < 5; j++) {
            int xx = x + 2 - j;
            if (xx < 0 || xx >= 24) continue;
            num += ob[((long)((yy * 24 + xx) * 25 + i * 5 + j)) * 48 + td * 3 + ch];
            den++;
        }
    }
    out[idx] = num / (float)den;
}

// ---------------- final loss reduce ----------------
__global__ __launch_bounds__(64) void loss_kernel(const float* __restrict__ lp,
                                                  float* __restrict__ out) {
    int t = threadIdx.x;
    float s = 0.0f;
    for (int e = t; e < 576; e += 64) s += lp[e];
#pragma unroll
    for (int d = 32; d >= 1; d >>= 1) s += __shfl_xor(s, d);
    if (t == 0) out[27648] = s / 691200.0f;
}

// ---------------- launch ----------------
extern "C" void kernel_launch(void* const* d_in, const int* in_sizes, int n_in,
                              void* d_out, int out_size, void* d_ws, size_t ws_size,
                              hipStream_t stream) {
    const float* x      = (const float*)d_in[0];
    const float* design = (const float*)d_in[1];
    const float* gt     = (const float*)d_in[2];
    const float* w1     = (const float*)d_in[3];
    const float* b1     = (const float*)d_in[4];
    const float* w2     = (const float*)d_in[5];
    const float* b2     = (const float*)d_in[6];
    const float* w3     = (const float*)d_in[7];
    const float* b3     = (const float*)d_in[8];
    const float* wf     = (const float*)d_in[9];
    const float* bf     = (const float*)d_in[10];
    float* out = (float*)d_out;
    char* wsb  = (char*)d_ws;

    float* part = (float*)(wsb + OFF_PART);
    char*  x2t  = wsb + OFF_X2T;
    float* wtT  = (float*)(wsb + OFF_WTT);   // overlaps X2T (dead by then)
    float* act  = (float*)(wsb + OFF_ACT);
    float* ob   = (float*)(wsb + OFF_OB);
    float* lp   = (float*)(wsb + OFF_LP);

    // conv1: K=1440 (45 chunks), ksplit=15 x cps=3 -> 480 blocks
    im2col_kernel<<<102, 256, 0, stream>>>(x, x2t, 45 * 576);
    conv_mfma8_kernel<0><<<dim3(8, 4, 15), 256, 0, stream>>>(x2t, w1, part, 1440, 3, 1024);
    finalize_kernel<<<2304, 256, 0, stream>>>(part, b1, act, 589824, 15);
    // conv2: K=9216 (288 chunks), ksplit=16 x cps=18 -> 512 blocks (2/CU)
    im2col_kernel<<<648, 256, 0, stream>>>(act, x2t, 288 * 576);
    conv_mfma8_kernel<0><<<dim3(8, 4, 16), 256, 0, stream>>>(x2t, w2, part, 9216, 18, 1024);
    finalize_kernel<<<2304, 256, 0, stream>>>(part, b2, act, 589824, 16);
    // conv3
    im2col_kernel<<<648, 256, 0, stream>>>(act, x2t, 288 * 576);
    conv_mfma8_kernel<0><<<dim3(8, 4, 16), 256, 0, stream>>>(x2t, w3, part, 9216, 18, 1024);
    finalize_kernel<<<2304, 256, 0, stream>>>(part, b3, act, 589824, 16);
    // convf: cout=6400, ksplit=4 x cps=72 -> 800 blocks, XCD-chunk swizzled
    im2col_kernel<<<648, 256, 0, stream>>>(act, x2t, 288 * 576);
    conv_mfma8_kernel<1><<<800, 256, 0, stream>>>(x2t, wf, part, 9216, 72, 6400);
    tanh_tr_kernel<<<dim3(100, 9), dim3(64, 4), 0, stream>>>(part, bf, wtT, 4);

    stagec_kernel<<<576, 256, 0, stream>>>(design, wtT, x, gt, ob, lp);
    fold_kernel<<<108, 256, 0, stream>>>(ob, out);
    loss_kernel<<<1, 64, 0, stream>>>(lp, out);
}